// Round 11
// baseline (167.180 us; speedup 1.0000x reference)
//
#include <hip/hip_runtime.h>
#include <hip/hip_bf16.h>

// NonLocalBlock for MI355X. B=4, CIN=256, C=128, H=W=64 -> N=4096.
// split + wsplit_all -> proj_mfma (3-pass bf16-split MFMA) ->
// attn: MFMA 32x32 flash, KVBLK=64, SINGLE-buffered K/V, 48KB LDS ->
//   3 blocks/CU (inter-block overlap), barrier-free compute phase,
//   XCD swizzle, defer-max, in-register P ->
// merge -> zgemm (split-bf16 MFMA + LN partials) -> stats -> LN+residual.

#define BB   4
#define CINC 256
#define CCH  128
#define NS   4096
#define LN_EPS 1e-5f

typedef unsigned short ushort_t;
typedef unsigned int   uint_t;
typedef __bf16 bf16x8 __attribute__((ext_vector_type(8)));
typedef float  f32x4  __attribute__((ext_vector_type(4)));
typedef float  f32x16 __attribute__((ext_vector_type(16)));

typedef const __attribute__((address_space(1))) void* gas_ptr;
typedef __attribute__((address_space(3))) void*       las_ptr;

__device__ __forceinline__ void gload16(const ushort_t* g, ushort_t* l) {
    __builtin_amdgcn_global_load_lds((gas_ptr)g, (las_ptr)l, 16, 0, 0);
}

__device__ __forceinline__ float4 ld4(const float* p) { return *reinterpret_cast<const float4*>(p); }
__device__ __forceinline__ void   st4(float* p, float4 v) { *reinterpret_cast<float4*>(p) = v; }

__device__ __forceinline__ ushort_t f2bf(float f) {
    __hip_bfloat16 h = __float2bfloat16(f);
    return *reinterpret_cast<ushort_t*>(&h);
}
__device__ __forceinline__ float bf2f(ushort_t u) {
    __hip_bfloat16 h = *reinterpret_cast<__hip_bfloat16*>(&u);
    return __bfloat162float(h);
}
__device__ __forceinline__ uint_t pk2(float a, float b) {
    return (uint_t)f2bf(a) | ((uint_t)f2bf(b) << 16);
}

// split 8 fp32 -> hi/lo bf16 words
__device__ __forceinline__ void split8(const float* v, uint_t* hw, uint_t* lw) {
#pragma unroll
    for (int jj = 0; jj < 4; ++jj) {
        ushort_t h0 = f2bf(v[2 * jj]);
        ushort_t h1 = f2bf(v[2 * jj + 1]);
        ushort_t e0 = f2bf(v[2 * jj] - bf2f(h0));
        ushort_t e1 = f2bf(v[2 * jj + 1] - bf2f(h1));
        hw[jj] = (uint_t)h0 | ((uint_t)h1 << 16);
        lw[jj] = (uint_t)e0 | ((uint_t)e1 << 16);
    }
}

// ---------------------------------------------------------------------------
// Kernel 0a: x [B][CIN][NS] fp32 -> xTh/xTl [B][NS][CIN] bf16 split, swizzled.
// ---------------------------------------------------------------------------
__global__ __launch_bounds__(256) void split_kernel(
    const float* __restrict__ x,
    ushort_t* __restrict__ xTh, ushort_t* __restrict__ xTl)
{
    __shared__ float T[64 * 68];

    const int tid = threadIdx.x;
    const int n0  = blockIdx.x * 64;
    const int k0  = blockIdx.y * 64;
    const int b   = blockIdx.z;

#pragma unroll
    for (int u = 0; u < 4; ++u) {
        int fi = u * 256 + tid;
        int k  = fi >> 4;
        int c4 = fi & 15;
        float4 v = ld4(&x[(size_t)(b * CINC + k0 + k) * NS + n0 + c4 * 4]);
        T[(c4 * 4 + 0) * 68 + k] = v.x;
        T[(c4 * 4 + 1) * 68 + k] = v.y;
        T[(c4 * 4 + 2) * 68 + k] = v.z;
        T[(c4 * 4 + 3) * 68 + k] = v.w;
    }
    __syncthreads();

#pragma unroll
    for (int u = 0; u < 2; ++u) {
        int fi = u * 256 + tid;
        int n  = fi >> 3;
        int j  = fi & 7;
        float4 a0 = ld4(&T[n * 68 + j * 8]);
        float4 a1 = ld4(&T[n * 68 + j * 8 + 4]);
        float v[8] = {a0.x, a0.y, a0.z, a0.w, a1.x, a1.y, a1.z, a1.w};
        uint_t hw[4], lw[4];
        split8(v, hw, lw);
        size_t base = (size_t)(b * NS + n0 + n) * CINC + k0 + ((j ^ (n & 7)) * 8);
        *reinterpret_cast<uint4*>(&xTh[base]) = make_uint4(hw[0], hw[1], hw[2], hw[3]);
        *reinterpret_cast<uint4*>(&xTl[base]) = make_uint4(lw[0], lw[1], lw[2], lw[3]);
    }
}

// ---------------------------------------------------------------------------
// Kernel 0b: all weights -> bf16 split, swizzled.
// Tasks [0, 384*32): stacked Wt/Wp/Wg -> Whs/Wls.
// Tasks [384*32, +256*16): Wz -> Wzh/Wzl.
// ---------------------------------------------------------------------------
__global__ __launch_bounds__(256) void wsplit_all_kernel(
    const float* __restrict__ Wt, const float* __restrict__ Wp,
    const float* __restrict__ Wg, const float* __restrict__ Wz,
    ushort_t* __restrict__ Whs, ushort_t* __restrict__ Wls,
    ushort_t* __restrict__ Wzh, ushort_t* __restrict__ Wzl)
{
    int task = blockIdx.x * 256 + threadIdx.x;   // 16384 tasks
    if (task < 384 * 32) {
        int o = task >> 5;
        int j = task & 31;
        int mid = o >> 7;
        int r   = o & 127;
        const float* Wsel = (mid == 0) ? Wt : (mid == 1) ? Wp : Wg;
        float4 a0 = ld4(&Wsel[(size_t)r * CINC + j * 8]);
        float4 a1 = ld4(&Wsel[(size_t)r * CINC + j * 8 + 4]);
        float v[8] = {a0.x, a0.y, a0.z, a0.w, a1.x, a1.y, a1.z, a1.w};
        uint_t hw[4], lw[4];
        split8(v, hw, lw);
        int kb = j >> 3, jj8 = j & 7;
        size_t base = (size_t)o * CINC + kb * 64 + ((jj8 ^ (o & 7)) * 8);
        *reinterpret_cast<uint4*>(&Whs[base]) = make_uint4(hw[0], hw[1], hw[2], hw[3]);
        *reinterpret_cast<uint4*>(&Wls[base]) = make_uint4(lw[0], lw[1], lw[2], lw[3]);
    } else {
        int t2 = task - 384 * 32;   // 0..4095
        int o = t2 >> 4;
        int j = t2 & 15;
        float4 a0 = ld4(&Wz[(size_t)o * CCH + j * 8]);
        float4 a1 = ld4(&Wz[(size_t)o * CCH + j * 8 + 4]);
        float v[8] = {a0.x, a0.y, a0.z, a0.w, a1.x, a1.y, a1.z, a1.w};
        uint_t hw[4], lw[4];
        split8(v, hw, lw);
        size_t base = (size_t)o * CCH + (j >> 3) * 64 + (((j & 7) ^ (o & 7)) * 8);
        *reinterpret_cast<uint4*>(&Wzh[base]) = make_uint4(hw[0], hw[1], hw[2], hw[3]);
        *reinterpret_cast<uint4*>(&Wzl[base]) = make_uint4(lw[0], lw[1], lw[2], lw[3]);
    }
}

// ---------------------------------------------------------------------------
// Kernel 1: proj via 3-pass bf16-split MFMA. V epilogue writes 64-n-window
// swizzled V^T (chunk position = (nj&7)^(c&7)) for attn's KVBLK=64 staging.
// ---------------------------------------------------------------------------
__global__ __launch_bounds__(256) void proj_mfma_kernel(
    const ushort_t* __restrict__ xTh, const ushort_t* __restrict__ xTl,
    const ushort_t* __restrict__ Whs, const ushort_t* __restrict__ Wls,
    const float* __restrict__ bt, const float* __restrict__ bp,
    const float* __restrict__ bg,
    ushort_t* __restrict__ Qhi, ushort_t* __restrict__ Qlo,
    ushort_t* __restrict__ KhiS, ushort_t* __restrict__ KloS,
    ushort_t* __restrict__ VtS)
{
    __shared__ __align__(16) char smem[65536];
    ushort_t* Wh_l = (ushort_t*)smem;              // [128 o][64 k]
    ushort_t* Wl_l = (ushort_t*)(smem + 16384);
    ushort_t* Xh_l = (ushort_t*)(smem + 32768);    // [128 n][64 k]
    ushort_t* Xl_l = (ushort_t*)(smem + 49152);
    float*    T    = (float*)smem;                 // epilogue [64][132]

    const int tid  = threadIdx.x;
    const int w    = tid >> 6;
    const int lane = tid & 63;
    const int l31  = lane & 31;
    const int h    = lane >> 5;
    const int n0   = blockIdx.x * 128;
    const int og   = blockIdx.y;    // 0 theta, 1 phi, 2 g
    const int b    = blockIdx.z;

    const float* bsel = (og == 0) ? bt : (og == 1) ? bp : bg;

    f32x16 acc[4];
#pragma unroll
    for (int ng = 0; ng < 4; ++ng)
#pragma unroll
        for (int r = 0; r < 16; ++r) acc[ng][r] = 0.f;

    const int ol   = w * 32 + l31;
    const int swzq = l31 & 7;

    for (int kb = 0; kb < 4; ++kb) {
        if (kb > 0) __syncthreads();
#pragma unroll
        for (int p = 0; p < 4; ++p) {
            int e  = p * 2048 + tid * 8;
            int rr = e >> 6;
            int kk = e & 63;
            gload16(Whs + (size_t)(og * 128 + rr) * CINC + kb * 64 + kk, Wh_l + e);
            gload16(Wls + (size_t)(og * 128 + rr) * CINC + kb * 64 + kk, Wl_l + e);
            gload16(xTh + (size_t)(b * NS + n0 + rr) * CINC + kb * 64 + kk, Xh_l + e);
            gload16(xTl + (size_t)(b * NS + n0 + rr) * CINC + kb * 64 + kk, Xl_l + e);
        }
        __syncthreads();

        __builtin_amdgcn_s_setprio(1);
#pragma unroll
        for (int k16 = 0; k16 < 4; ++k16) {
            int c8  = k16 * 2 + h;
            int swz = c8 ^ swzq;
            bf16x8 ah = *reinterpret_cast<const bf16x8*>(&Wh_l[ol * 64 + swz * 8]);
            bf16x8 al = *reinterpret_cast<const bf16x8*>(&Wl_l[ol * 64 + swz * 8]);
#pragma unroll
            for (int ng = 0; ng < 4; ++ng) {
                int nl = ng * 32 + l31;
                bf16x8 xh = *reinterpret_cast<const bf16x8*>(&Xh_l[nl * 64 + swz * 8]);
                bf16x8 xl = *reinterpret_cast<const bf16x8*>(&Xl_l[nl * 64 + swz * 8]);
                acc[ng] = __builtin_amdgcn_mfma_f32_32x32x16_bf16(ah, xh, acc[ng], 0, 0, 0);
                acc[ng] = __builtin_amdgcn_mfma_f32_32x32x16_bf16(ah, xl, acc[ng], 0, 0, 0);
                acc[ng] = __builtin_amdgcn_mfma_f32_32x32x16_bf16(al, xh, acc[ng], 0, 0, 0);
            }
        }
        __builtin_amdgcn_s_setprio(0);
    }

    float bv[16];
#pragma unroll
    for (int r = 0; r < 16; ++r)
        bv[r] = bsel[w * 32 + (r & 3) + 8 * (r >> 2) + 4 * h];

    __syncthreads();

    if (og < 2) {
        ushort_t* H = (og == 0) ? Qhi : KhiS;
        ushort_t* L = (og == 0) ? Qlo : KloS;
#pragma unroll
        for (int pass = 0; pass < 2; ++pass) {
#pragma unroll
            for (int ngh = 0; ngh < 2; ++ngh) {
                int ng = pass * 2 + ngh;
                int nl = ngh * 32 + l31;
#pragma unroll
                for (int r = 0; r < 16; ++r) {
                    int o_in = w * 32 + (r & 3) + 8 * (r >> 2) + 4 * h;
                    T[nl * 132 + o_in] = acc[ng][r] + bv[r];
                }
            }
            __syncthreads();
#pragma unroll
            for (int u = 0; u < 4; ++u) {
                int fi = u * 256 + tid;
                int n  = fi >> 4;
                int j  = fi & 15;
                float4 a0 = ld4(&T[n * 132 + j * 8]);
                float4 a1 = ld4(&T[n * 132 + j * 8 + 4]);
                float v[8] = {a0.x, a0.y, a0.z, a0.w, a1.x, a1.y, a1.z, a1.w};
                uint_t hw[4], lw[4];
                split8(v, hw, lw);
                int n_glob = n0 + pass * 64 + n;
                int idx = (og == 1) ? ((j & 8) | ((j & 7) ^ (n & 7))) : j;
                size_t base = (size_t)(b * NS + n_glob) * CCH + idx * 8;
                *reinterpret_cast<uint4*>(&H[base]) = make_uint4(hw[0], hw[1], hw[2], hw[3]);
                *reinterpret_cast<uint4*>(&L[base]) = make_uint4(lw[0], lw[1], lw[2], lw[3]);
            }
            __syncthreads();
        }
    } else {
#pragma unroll
        for (int pass = 0; pass < 2; ++pass) {
            if ((w >> 1) == pass) {
#pragma unroll
                for (int ng = 0; ng < 4; ++ng) {
                    int nl = ng * 32 + l31;
#pragma unroll
                    for (int r = 0; r < 16; ++r) {
                        int c_loc = (w & 1) * 32 + (r & 3) + 8 * (r >> 2) + 4 * h;
                        T[c_loc * 132 + nl] = acc[ng][r] + bv[r];
                    }
                }
            }
            __syncthreads();
#pragma unroll
            for (int u = 0; u < 4; ++u) {
                int fi = u * 256 + tid;
                int c_loc = fi >> 4;
                int nj    = fi & 15;
                float4 a0 = ld4(&T[c_loc * 132 + nj * 8]);
                float4 a1 = ld4(&T[c_loc * 132 + nj * 8 + 4]);
                int c = pass * 64 + c_loc;
                uint4 wv;
                wv.x = pk2(a0.x, a0.y);
                wv.y = pk2(a0.z, a0.w);
                wv.z = pk2(a1.x, a1.y);
                wv.w = pk2(a1.z, a1.w);
                // 64-n window swizzle for attn's KVBLK=64 linear gload_lds
                size_t base = (size_t)(b * CCH + c) * NS + n0 + (nj >> 3) * 64
                            + (((nj & 7) ^ (c & 7)) * 8);
                *reinterpret_cast<uint4*>(&VtS[base]) = wv;
            }
            __syncthreads();
        }
    }
}

// ---------------------------------------------------------------------------
// Kernel 2: MFMA 32x32 flash attention. QTILE=128 (4 waves x 32 q), KVBLK=64,
// SINGLE-buffered K/V via global_load_lds. LDS 48KB -> 3 blocks/CU; compute
// phase is barrier-free; 2 barriers/iter around staging. Inter-block overlap
// hides the drain. XCD swizzle + defer-max + in-register P.
// ---------------------------------------------------------------------------
__global__ __launch_bounds__(256, 3) void attn_kernel(
    const ushort_t* __restrict__ Qhi, const ushort_t* __restrict__ Qlo,
    const ushort_t* __restrict__ KhiS, const ushort_t* __restrict__ KloS,
    const ushort_t* __restrict__ VtS, float* __restrict__ Yp,
    float* __restrict__ ML, int NT)
{
    __shared__ __align__(16) char smem[49152];
    // Kh: 0..16K ; Kl: 16K..32K ; V: 32K..48K

    const int tid  = threadIdx.x;
    const int w    = tid >> 6;      // wave 0..3 -> q-strip w*32
    const int lane = tid & 63;
    const int l31  = lane & 31;
    const int h    = lane >> 5;

    // XCD-aware swizzle (bijective for the 512-block nsplit=4 grid)
    int qx, sp, b;
    {
        int lin = (blockIdx.z * gridDim.y + blockIdx.y) * gridDim.x + blockIdx.x;
        if (gridDim.x * gridDim.y * gridDim.z == 512) {
            int xcd  = lin & 7;
            int idx  = lin >> 3;
            int pair = xcd * 2 + (idx >> 5);
            qx = idx & 31;
            b  = pair >> 2;
            sp = pair & 3;
        } else {
            qx = blockIdx.x; sp = blockIdx.y; b = blockIdx.z;
        }
    }
    const int n0 = qx * 128;

    bf16x8 qh[8], ql[8];
    {
        const ushort_t* qrh = Qhi + (size_t)(b * NS + n0 + w * 32 + l31) * CCH;
        const ushort_t* qrl = Qlo + (size_t)(b * NS + n0 + w * 32 + l31) * CCH;
#pragma unroll
        for (int cst = 0; cst < 8; ++cst) {
            qh[cst] = *reinterpret_cast<const bf16x8*>(qrh + cst * 16 + h * 8);
            ql[cst] = *reinterpret_cast<const bf16x8*>(qrl + cst * 16 + h * 8);
        }
    }

    f32x16 yacc[4];
#pragma unroll
    for (int cb = 0; cb < 4; ++cb)
#pragma unroll
        for (int r = 0; r < 16; ++r) yacc[cb][r] = 0.f;
    float m_run = -1e30f, l_run = 0.f;

    const ushort_t* Khg = KhiS + (size_t)b * NS * CCH;
    const ushort_t* Klg = KloS + (size_t)b * NS * CCH;
    const ushort_t* Vtg = VtS + (size_t)b * CCH * NS;

    const int ktbase = sp * NT;
    const int swzq = l31 & 7;

    ushort_t* KhL = (ushort_t*)smem;
    ushort_t* KlL = (ushort_t*)(smem + 16384);
    ushort_t* VL  = (ushort_t*)(smem + 32768);

    auto gload_tile = [&](int ktg) {
        const size_t koff = (size_t)ktg * 8192;   // 64 rows * 128 c (ushorts)
        const int m0 = ktg * 64;
#pragma unroll
        for (int i = 0; i < 4; ++i) {
            int off = i * 2048 + tid * 8;
            gload16(Khg + koff + off, KhL + off);
            gload16(Klg + koff + off, KlL + off);
            int cr = off >> 6;
            int cw = off & 63;
            gload16(Vtg + (size_t)cr * NS + m0 + cw, VL + off);
        }
    };

    // prologue: tile 0 (K and V together)
    gload_tile(ktbase);
    __syncthreads();   // drain + visible

    for (int kt = 0; kt < NT; ++kt) {
        // ---- QK^T: S^T[64k][32q], 3-pass split-bf16, 32x32x16 MFMA
        f32x16 sacc[2];
#pragma unroll
        for (int k2 = 0; k2 < 2; ++k2)
#pragma unroll
            for (int r = 0; r < 16; ++r) sacc[k2][r] = 0.f;

        __builtin_amdgcn_s_setprio(1);
#pragma unroll
        for (int cst = 0; cst < 8; ++cst) {
            int cc  = cst * 2 + h;
            int swz = (cc & 8) | ((cc & 7) ^ swzq);
#pragma unroll
            for (int k2 = 0; k2 < 2; ++k2) {
                int addr = (k2 * 32 + l31) * 128 + swz * 8;
                bf16x8 ah = *reinterpret_cast<const bf16x8*>(&KhL[addr]);
                bf16x8 al = *reinterpret_cast<const bf16x8*>(&KlL[addr]);
                sacc[k2] = __builtin_amdgcn_mfma_f32_32x32x16_bf16(ah, qh[cst], sacc[k2], 0, 0, 0);
                sacc[k2] = __builtin_amdgcn_mfma_f32_32x32x16_bf16(al, qh[cst], sacc[k2], 0, 0, 0);
                sacc[k2] = __builtin_amdgcn_mfma_f32_32x32x16_bf16(ah, ql[cst], sacc[k2], 0, 0, 0);
            }
        }
        __builtin_amdgcn_s_setprio(0);

        // ---- online softmax (lane owns q = w*32+l31)
        float mx = sacc[0][0];
#pragma unroll
        for (int r = 1; r < 16; ++r) mx = fmaxf(mx, sacc[0][r]);
#pragma unroll
        for (int r = 0; r < 16; ++r) mx = fmaxf(mx, sacc[1][r]);
        mx = fmaxf(mx, __shfl_xor(mx, 32));

        const bool defer = __all(mx - m_run <= 8.0f);
        float mref, alpha;
        if (defer) { mref = m_run; alpha = 1.0f; }
        else       { mref = fmaxf(m_run, mx); alpha = __expf(m_run - mref); }

        // ---- P = exp(S - mref), pack to PV B-frags in registers
        bf16x8 pb[4];
        float psum = 0.f;
#pragma unroll
        for (int k2 = 0; k2 < 2; ++k2) {
            float pe[16];
#pragma unroll
            for (int r = 0; r < 16; ++r) {
                pe[r] = __expf(sacc[k2][r] - mref);
                psum += pe[r];
            }
#pragma unroll
            for (int a = 0; a < 2; ++a) {
                uint_t w0 = pk2(pe[8 * a + 0], pe[8 * a + 1]);
                uint_t w1 = pk2(pe[8 * a + 2], pe[8 * a + 3]);
                uint_t w2 = pk2(pe[8 * a + 4], pe[8 * a + 5]);
                uint_t w3 = pk2(pe[8 * a + 6], pe[8 * a + 7]);
                uint_t s0 = (uint_t)__shfl_xor((int)w0, 32);
                uint_t s1 = (uint_t)__shfl_xor((int)w1, 32);
                uint_t s2 = (uint_t)__shfl_xor((int)w2, 32);
                uint_t s3 = (uint_t)__shfl_xor((int)w3, 32);
                uint_t u0 = h ? s2 : w0;
                uint_t u1 = h ? s3 : w1;
                uint_t u2 = h ? w2 : s0;
                uint_t u3 = h ? w3 : s1;
                uint4 packed = make_uint4(u0, u1, u2, u3);
                pb[k2 * 2 + a] = *reinterpret_cast<bf16x8*>(&packed);
            }
        }
        psum += __shfl_xor(psum, 32);

        if (defer) {
            l_run += psum;
        } else {
            l_run = l_run * alpha + psum;
            m_run = mref;
#pragma unroll
            for (int cb = 0; cb < 4; ++cb)
#pragma unroll
                for (int r = 0; r < 16; ++r) yacc[cb][r] *= alpha;
        }

        // ---- PV: Y^T[c][q] += V^T x P^T  (V resident since staging barrier)
        __builtin_amdgcn_s_setprio(1);
#pragma unroll
        for (int cb = 0; cb < 4; ++cb) {
            int crow = (cb * 32 + l31) * 64;
#pragma unroll
            for (int ks = 0; ks < 4; ++ks) {
                int kc = ks * 2 + h;
                bf16x8 av = *reinterpret_cast<const bf16x8*>(&VL[crow + (kc ^ swzq) * 8]);
                yacc[cb] = __builtin_amdgcn_mfma_f32_32x32x16_bf16(av, pb[ks], yacc[cb], 0, 0, 0);
            }
        }
        __builtin_amdgcn_s_setprio(0);

        __syncthreads();   // all readers done with this tile's LDS
        if (kt + 1 < NT) {
            gload_tile(ktbase + kt + 1);
            __syncthreads();   // drain + visible (overlap via other blocks on CU)
        }
    }

    // ---- epilogue: coalesced unnormalized-Y store via staged LDS (2 passes)
    float* stage = (float*)smem;   // [64][132] = 33.8 KB, fits in 48 KB
    float* Ybase = Yp + ((size_t)(sp * BB + b) * NS + n0) * CCH;
#pragma unroll
    for (int pass = 0; pass < 2; ++pass) {
        if ((w >> 1) == pass) {
            int qrow = (w & 1) * 32 + l31;
#pragma unroll
            for (int cb = 0; cb < 4; ++cb)
#pragma unroll
                for (int r = 0; r < 16; ++r) {
                    int c = cb * 32 + (r & 3) + 8 * (r >> 2) + 4 * h;
                    stage[qrow * 132 + c] = yacc[cb][r];
                }
        }
        __syncthreads();
#pragma unroll
        for (int u = 0; u < 8; ++u) {
            int idx = u * 256 + tid;
            int row = idx >> 5;
            int c4  = idx & 31;
            st4(&Ybase[(size_t)(pass * 64 + row) * CCH + c4 * 4],
                ld4(&stage[row * 132 + c4 * 4]));
        }
        __syncthreads();
    }
    if (h == 0) {
        size_t mi = ((size_t)(sp * BB + b) * NS + n0 + w * 32 + l31) * 2;
        ML[mi + 0] = m_run;
        ML[mi + 1] = l_run;
    }
}

// ---------------------------------------------------------------------------
// Kernel 2b: merge KV-split partials -> normalized Ym, split bf16, swizzled.
// ---------------------------------------------------------------------------
__global__ __launch_bounds__(256) void merge_kernel(
    const float* __restrict__ Yp, const float* __restrict__ ML,
    ushort_t* __restrict__ Ymh, ushort_t* __restrict__ Yml, int nsplit)
{
    const int total = BB * NS * (CCH / 8);    // 262144
    for (int t = blockIdx.x * 256 + threadIdx.x; t < total;
         t += gridDim.x * 256) {
        int b = t >> 16;
        int r = t & 65535;
        int n = r >> 4;
        int j = r & 15;

        float ms[4], ls[4];
        float m = -1e30f;
#pragma unroll
        for (int s = 0; s < 4; ++s) {
            if (s < nsplit) {
                size_t mi = ((size_t)(s * BB + b) * NS + n) * 2;
                ms[s] = ML[mi + 0];
                ls[s] = ML[mi + 1];
                m = fmaxf(m, ms[s]);
            }
        }
        float den = 0.f;
        float wt[4];
#pragma unroll
        for (int s = 0; s < 4; ++s) {
            if (s < nsplit) {
                wt[s] = __expf(ms[s] - m);
                den += ls[s] * wt[s];
            }
        }
        float inv = 1.0f / den;

        float acc[8] = {0.f, 0.f, 0.f, 0.f, 0.f, 0.f, 0.f, 0.f};
#pragma unroll
        for (int s = 0; s < 4; ++s) {
            if (s < nsplit) {
                float a = wt[s] * inv;
                const float* yr = &Yp[((size_t)(s * BB + b) * NS + n) * CCH + j * 8];
                float4 y0 = ld4(yr);
                float4 y1 = ld4(yr + 4);
                acc[0] += a * y0.x; acc[1] += a * y0.y;
                acc[2] += a * y0.z; acc[3] += a * y0.w;
                acc[4] += a * y1.x; acc[5] += a * y1.y;
                acc[6] += a * y1.z; acc[7] += a * y1.w;
            }
        }
        uint_t hw[4], lw[4];
        split8(acc, hw, lw);
        size_t base = (size_t)(b * NS + n) * CCH + (j >> 3) * 64
                    + (((j & 7) ^ (n & 7)) * 8);
        *reinterpret_cast<uint4*>(&Ymh[base]) = make_uint4(hw[0], hw[1], hw[2], hw[3]);
        *reinterpret_cast<uint4*>(&Yml[base]) = make_uint4(lw[0], lw[1], lw[2], lw[3]);
    }
}

// ---------------------------------------------------------------------------
// Kernel 3: z = Wz . Ym + bz via 3-pass split-bf16 MFMA, + LN partials.
// ---------------------------------------------------------------------------
__global__ __launch_bounds__(256) void zgemm_kernel(
    const ushort_t* __restrict__ Ymh, const ushort_t* __restrict__ Yml,
    const ushort_t* __restrict__ Wzh, const ushort_t* __restrict__ Wzl,
    const float* __restrict__ bz, float* __restrict__ Z,
    float* __restrict__ partials)
{
    __shared__ __align__(16) char smem[65536];
    ushort_t* Wh_l = (ushort_t*)smem;
    ushort_t* Wl_l = (ushort_t*)(smem + 16384);
    ushort_t* Yh_l = (ushort_t*)(smem + 32768);
    ushort_t* Yl_l = (ushort_t*)(smem + 49152);
    __shared__ float red[8];

    const int tid  = threadIdx.x;
    const int w    = tid >> 6;
    const int lane = tid & 63;
    const int l31  = lane & 31;
    const int h    = lane >> 5;
    const int n0   = blockIdx.x * 128;
    const int o0   = blockIdx.y * 128;
    const int b    = blockIdx.z;

    f32x16 acc[4];
#pragma unroll
    for (int ng = 0; ng < 4; ++ng)
#pragma unroll
        for (int r = 0; r < 16; ++r) acc[ng][r] = 0.f;

    const int ol   = w * 32 + l31;
    const int swzq = l31 & 7;

    for (int kb = 0; kb < 2; ++kb) {
        if (kb > 0) __syncthreads();
#pragma unroll
        for (int p = 0; p < 4; ++p) {
            int e  = p * 2048 + tid * 8;
            int rr = e >> 6;
            int kk = e & 63;
            gload16(Wzh + (size_t)(o0 + rr) * CCH + kb * 64 + kk, Wh_l + e);
            gload16(Wzl + (size_t)(o0 + rr) * CCH + kb * 64 + kk, Wl_l + e);
            gload16(Ymh + (size_t)(b * NS + n0 + rr) * CCH + kb * 64 + kk, Yh_l + e);
            gload16(Yml + (size_t)(b * NS + n0 + rr) * CCH + kb * 64 + kk, Yl_l + e);
        }
        __syncthreads();

        __builtin_amdgcn_s_setprio(1);
#pragma unroll
        for (int k16 = 0; k16 < 4; ++k16) {
            int c8  = k16 * 2 + h;
            int swz = c8 ^ swzq;
            bf16x8 ah = *reinterpret_cast<const bf16x8*>(&Wh_l[ol * 64 + swz * 8]);
            bf16x8 al = *reinterpret_cast<const bf16x8*>(&Wl_l[ol * 64 + swz * 8]);
#pragma unroll
            for (int ng = 0; ng < 4; ++ng) {
                int nl = ng * 32 + l31;
                bf16x8 yh = *reinterpret_cast<const bf16x8*>(&Yh_l[nl * 64 + swz * 8]);
                bf16x8 yl = *reinterpret_cast<const bf16x8*>(&Yl_l[nl * 64 + swz * 8]);
                acc[ng] = __builtin_amdgcn_mfma_f32_32x32x16_bf16(ah, yh, acc[ng], 0, 0, 0);
                acc[ng] = __builtin_amdgcn_mfma_f32_32x32x16_bf16(ah, yl, acc[ng], 0, 0, 0);
                acc[ng] = __builtin_amdgcn_mfma_f32_32x32x16_bf16(al, yh, acc[ng], 0, 0, 0);
            }
        }
        __builtin_amdgcn_s_setprio(0);
    }

    float s = 0.f, s2 = 0.f;
#pragma unroll
    for (int r = 0; r < 16; ++r) {
        int o = o0 + w * 32 + (r & 3) + 8 * (r >> 2) + 4 * h;
        float bias = bz[o];
        float* zrow = &Z[(size_t)(b * CINC + o) * NS + n0 + l31];
#pragma unroll
        for (int ng = 0; ng < 4; ++ng) {
            float v = acc[ng][r] + bias;
            zrow[ng * 32] = v;
            s  += v;
            s2 += v * v;
        }
    }
#pragma unroll
    for (int off = 1; off < 64; off <<= 1) {
        s  += __shfl_xor(s, off);
        s2 += __shfl_xor(s2, off);
    }
    if (lane == 0) { red[w * 2] = s; red[w * 2 + 1] = s2; }
    __syncthreads();
    if (tid == 0) {
        float ts  = red[0] + red[2] + red[4] + red[6];
        float ts2 = red[1] + red[3] + red[5] + red[7];
        int pidx = (b * 2 + blockIdx.y) * 32 + blockIdx.x;
        partials[pidx * 2 + 0] = ts;
        partials[pidx * 2 + 1] = ts2;
    }
}

// ---------------------------------------------------------------------------
// Kernel 4: reduce partials (64 per batch) -> per-batch (mean, rstd).
// ---------------------------------------------------------------------------
__global__ void ln_stats_kernel(const float* __restrict__ partials,
                                float* __restrict__ stats)
{
    const int b = blockIdx.x;
    const int t = threadIdx.x;  // 64
    float s  = partials[(size_t)(b * 64 + t) * 2 + 0];
    float s2 = partials[(size_t)(b * 64 + t) * 2 + 1];
#pragma unroll
    for (int off = 1; off < 64; off <<= 1) {
        s  += __shfl_xor(s, off);
        s2 += __shfl_xor(s2, off);
    }
    if (t == 0) {
        const float M = 1048576.f;
        float mean = s / M;
        float var  = s2 / M - mean * mean;
        stats[b * 2 + 0] = mean;
        stats[b * 2 + 1] = rsqrtf(var + LN_EPS);
    }
}

// ---------------------------------------------------------------------------
// Kernel 5: out = (z - mean)*rstd*gamma + beta + x
// ---------------------------------------------------------------------------
__global__ __launch_bounds__(256) void final_kernel(
    const float* __restrict__ Z, const float* __restrict__ x,
    const float* __restrict__ gamma, const float* __restrict__ beta,
    const float* __restrict__ stats, float* __restrict__ out)
{
    const int total4 = BB * CINC * NS / 4;
    for (int i4 = blockIdx.x * 256 + threadIdx.x; i4 < total4;
         i4 += gridDim.x * 256) {
        int b  = i4 >> 18;
        int r4 = i4 & ((1 << 18) - 1);
        float mean = stats[b * 2 + 0];
        float rstd = stats[b * 2 + 1];
        float4 zv = ld4(&Z[(size_t)i4 * 4]);
        float4 xv = ld4(&x[(size_t)i4 * 4]);
        float4 gv = ld4(&gamma[(size_t)r4 * 4]);
        float4 bv = ld4(&beta[(size_t)r4 * 4]);
        float4 o;
        o.x = (zv.x - mean) * rstd * gv.x + bv.x + xv.x;
        o.y = (zv.y - mean) * rstd * gv.y + bv.y + xv.y;
        o.z = (zv.z - mean) * rstd * gv.z + bv.z + xv.z;
        o.w = (zv.w - mean) * rstd * gv.w + bv.w + xv.w;
        st4(&out[(size_t)i4 * 4], o);
    }
}

extern "C" void kernel_launch(void* const* d_in, const int* in_sizes, int n_in,
                              void* d_out, int out_size, void* d_ws, size_t ws_size,
                              hipStream_t stream)
{
    const float* x     = (const float*)d_in[0];
    const float* Wg    = (const float*)d_in[1];
    const float* bg    = (const float*)d_in[2];
    const float* Wt    = (const float*)d_in[3];
    const float* bt    = (const float*)d_in[4];
    const float* Wp    = (const float*)d_in[5];
    const float* bp    = (const float*)d_in[6];
    const float* Wz    = (const float*)d_in[7];
    const float* bz    = (const float*)d_in[8];
    const float* gamma = (const float*)d_in[9];
    const float* beta  = (const float*)d_in[10];
    float* out = (float*)d_out;

    const size_t SZH = (size_t)BB * NS * CCH * sizeof(ushort_t);  // 4 MB
    const size_t WZB = (size_t)CINC * CCH * sizeof(ushort_t);     // 64 KB
    const size_t need4 = 5 * SZH
                       + (size_t)4 * BB * NS * CCH * sizeof(float)
                       + (size_t)4 * BB * NS * 2 * sizeof(float)
                       + (size_t)BB * 64 * 2 * sizeof(float)
                       + 2 * WZB + 512;
    const int nsplit = (ws_size >= need4) ? 4 : 2;
    const int NT = (NS / 64) / nsplit;   // 64-key tiles per split

    char* p = (char*)d_ws;
    ushort_t* Qhi  = (ushort_t*)p; p += SZH;
    ushort_t* Qlo  = (ushort_t*)p; p += SZH;
    ushort_t* KhiS = (ushort_t*)p; p += SZH;
    ushort_t* KloS = (ushort_t*)p; p += SZH;
    ushort_t* VtS  = (ushort_t*)p; p += SZH;
    float* Yp = (float*)p; p += (size_t)nsplit * BB * NS * CCH * sizeof(float);
    float* ML = (float*)p; p += (size_t)nsplit * BB * NS * 2 * sizeof(float);
    float* partials = (float*)p; p += BB * 64 * 2 * sizeof(float);
    float* stats    = (float*)p; p += 64;
    ushort_t* Wzh = (ushort_t*)p; p += WZB;
    ushort_t* Wzl = (ushort_t*)p;

    // aliases (stream-ordered lifetimes):
    ushort_t* Ymh = (ushort_t*)Qhi;    // Q dead after attn
    ushort_t* Yml = (ushort_t*)Qlo;
    float*    Z   = (float*)Yp;        // Yp dead after merge

    // proj scratch aliases into Yp (dead until attn writes it)
    ushort_t* xTh = (ushort_t*)Yp;
    ushort_t* xTl = xTh + (size_t)BB * NS * CINC;
    ushort_t* Whs = (ushort_t*)((char*)Yp + 2 * (size_t)BB * NS * CINC * 2);
    ushort_t* Wls = Whs + (size_t)384 * CINC;

    split_kernel<<<dim3(NS / 64, CINC / 64, BB), 256, 0, stream>>>(x, xTh, xTl);
    wsplit_all_kernel<<<dim3(64), 256, 0, stream>>>(Wt, Wp, Wg, Wz,
                                                    Whs, Wls, Wzh, Wzl);
    proj_mfma_kernel<<<dim3(NS / 128, 3, BB), 256, 0, stream>>>(
        xTh, xTl, Whs, Wls, bt, bp, bg, Qhi, Qlo, KhiS, KloS, VtS);
    attn_kernel<<<dim3(NS / 128, nsplit, BB), 256, 0, stream>>>(
        Qhi, Qlo, KhiS, KloS, VtS, Yp, ML, NT);
    merge_kernel<<<dim3(1024), 256, 0, stream>>>(Yp, ML, Ymh, Yml, nsplit);
    zgemm_kernel<<<dim3(NS / 128, 2, BB), 256, 0, stream>>>(
        Ymh, Yml, Wzh, Wzl, bz, Z, partials);
    ln_stats_kernel<<<dim3(BB), 64, 0, stream>>>(partials, stats);
    final_kernel<<<dim3(2048), 256, 0, stream>>>(Z, x, gamma, beta, stats, out);
}

// Round 12
// 129.401 us; speedup vs baseline: 1.2920x; 1.2920x over previous
//
#include <hip/hip_runtime.h>
#include <hip/hip_bf16.h>

// NonLocalBlock for MI355X. B=4, CIN=256, C=128, H=W=64 -> N=4096.
// split + wsplit_all -> proj_mfma (3-pass bf16-split MFMA) ->
// attn: MFMA 32x32 flash, QTILE=256 (8 waves), KVBLK=64, all-dbuf
//   global_load_lds, ONE barrier/iter (r7 schedule, best measured) + XCD
//   swizzle, defer-max, in-register P ->
// merge -> zgemm (split-bf16 MFMA + LN partials) -> stats -> LN+residual.

#define BB   4
#define CINC 256
#define CCH  128
#define NS   4096
#define LN_EPS 1e-5f

typedef unsigned short ushort_t;
typedef unsigned int   uint_t;
typedef __bf16 bf16x8 __attribute__((ext_vector_type(8)));
typedef float  f32x4  __attribute__((ext_vector_type(4)));
typedef float  f32x16 __attribute__((ext_vector_type(16)));

typedef const __attribute__((address_space(1))) void* gas_ptr;
typedef __attribute__((address_space(3))) void*       las_ptr;

__device__ __forceinline__ void gload16(const ushort_t* g, ushort_t* l) {
    __builtin_amdgcn_global_load_lds((gas_ptr)g, (las_ptr)l, 16, 0, 0);
}

__device__ __forceinline__ float4 ld4(const float* p) { return *reinterpret_cast<const float4*>(p); }
__device__ __forceinline__ void   st4(float* p, float4 v) { *reinterpret_cast<float4*>(p) = v; }

__device__ __forceinline__ ushort_t f2bf(float f) {
    __hip_bfloat16 h = __float2bfloat16(f);
    return *reinterpret_cast<ushort_t*>(&h);
}
__device__ __forceinline__ float bf2f(ushort_t u) {
    __hip_bfloat16 h = *reinterpret_cast<__hip_bfloat16*>(&u);
    return __bfloat162float(h);
}
__device__ __forceinline__ uint_t pk2(float a, float b) {
    return (uint_t)f2bf(a) | ((uint_t)f2bf(b) << 16);
}

// split 8 fp32 -> hi/lo bf16 words
__device__ __forceinline__ void split8(const float* v, uint_t* hw, uint_t* lw) {
#pragma unroll
    for (int jj = 0; jj < 4; ++jj) {
        ushort_t h0 = f2bf(v[2 * jj]);
        ushort_t h1 = f2bf(v[2 * jj + 1]);
        ushort_t e0 = f2bf(v[2 * jj] - bf2f(h0));
        ushort_t e1 = f2bf(v[2 * jj + 1] - bf2f(h1));
        hw[jj] = (uint_t)h0 | ((uint_t)h1 << 16);
        lw[jj] = (uint_t)e0 | ((uint_t)e1 << 16);
    }
}

// ---------------------------------------------------------------------------
// Kernel 0a: x [B][CIN][NS] fp32 -> xTh/xTl [B][NS][CIN] bf16 split, swizzled.
// ---------------------------------------------------------------------------
__global__ __launch_bounds__(256) void split_kernel(
    const float* __restrict__ x,
    ushort_t* __restrict__ xTh, ushort_t* __restrict__ xTl)
{
    __shared__ float T[64 * 68];

    const int tid = threadIdx.x;
    const int n0  = blockIdx.x * 64;
    const int k0  = blockIdx.y * 64;
    const int b   = blockIdx.z;

#pragma unroll
    for (int u = 0; u < 4; ++u) {
        int fi = u * 256 + tid;
        int k  = fi >> 4;
        int c4 = fi & 15;
        float4 v = ld4(&x[(size_t)(b * CINC + k0 + k) * NS + n0 + c4 * 4]);
        T[(c4 * 4 + 0) * 68 + k] = v.x;
        T[(c4 * 4 + 1) * 68 + k] = v.y;
        T[(c4 * 4 + 2) * 68 + k] = v.z;
        T[(c4 * 4 + 3) * 68 + k] = v.w;
    }
    __syncthreads();

#pragma unroll
    for (int u = 0; u < 2; ++u) {
        int fi = u * 256 + tid;
        int n  = fi >> 3;
        int j  = fi & 7;
        float4 a0 = ld4(&T[n * 68 + j * 8]);
        float4 a1 = ld4(&T[n * 68 + j * 8 + 4]);
        float v[8] = {a0.x, a0.y, a0.z, a0.w, a1.x, a1.y, a1.z, a1.w};
        uint_t hw[4], lw[4];
        split8(v, hw, lw);
        size_t base = (size_t)(b * NS + n0 + n) * CINC + k0 + ((j ^ (n & 7)) * 8);
        *reinterpret_cast<uint4*>(&xTh[base]) = make_uint4(hw[0], hw[1], hw[2], hw[3]);
        *reinterpret_cast<uint4*>(&xTl[base]) = make_uint4(lw[0], lw[1], lw[2], lw[3]);
    }
}

// ---------------------------------------------------------------------------
// Kernel 0b: all weights -> bf16 split, swizzled.
// ---------------------------------------------------------------------------
__global__ __launch_bounds__(256) void wsplit_all_kernel(
    const float* __restrict__ Wt, const float* __restrict__ Wp,
    const float* __restrict__ Wg, const float* __restrict__ Wz,
    ushort_t* __restrict__ Whs, ushort_t* __restrict__ Wls,
    ushort_t* __restrict__ Wzh, ushort_t* __restrict__ Wzl)
{
    int task = blockIdx.x * 256 + threadIdx.x;   // 16384 tasks
    if (task < 384 * 32) {
        int o = task >> 5;
        int j = task & 31;
        int mid = o >> 7;
        int r   = o & 127;
        const float* Wsel = (mid == 0) ? Wt : (mid == 1) ? Wp : Wg;
        float4 a0 = ld4(&Wsel[(size_t)r * CINC + j * 8]);
        float4 a1 = ld4(&Wsel[(size_t)r * CINC + j * 8 + 4]);
        float v[8] = {a0.x, a0.y, a0.z, a0.w, a1.x, a1.y, a1.z, a1.w};
        uint_t hw[4], lw[4];
        split8(v, hw, lw);
        int kb = j >> 3, jj8 = j & 7;
        size_t base = (size_t)o * CINC + kb * 64 + ((jj8 ^ (o & 7)) * 8);
        *reinterpret_cast<uint4*>(&Whs[base]) = make_uint4(hw[0], hw[1], hw[2], hw[3]);
        *reinterpret_cast<uint4*>(&Wls[base]) = make_uint4(lw[0], lw[1], lw[2], lw[3]);
    } else {
        int t2 = task - 384 * 32;   // 0..4095
        int o = t2 >> 4;
        int j = t2 & 15;
        float4 a0 = ld4(&Wz[(size_t)o * CCH + j * 8]);
        float4 a1 = ld4(&Wz[(size_t)o * CCH + j * 8 + 4]);
        float v[8] = {a0.x, a0.y, a0.z, a0.w, a1.x, a1.y, a1.z, a1.w};
        uint_t hw[4], lw[4];
        split8(v, hw, lw);
        size_t base = (size_t)o * CCH + (j >> 3) * 64 + (((j & 7) ^ (o & 7)) * 8);
        *reinterpret_cast<uint4*>(&Wzh[base]) = make_uint4(hw[0], hw[1], hw[2], hw[3]);
        *reinterpret_cast<uint4*>(&Wzl[base]) = make_uint4(lw[0], lw[1], lw[2], lw[3]);
    }
}

// ---------------------------------------------------------------------------
// Kernel 1: proj via 3-pass bf16-split MFMA. V epilogue writes 64-n-window
// swizzled V^T (chunk position = (nj&7)^(c&7)) for attn's KVBLK=64 staging.
// ---------------------------------------------------------------------------
__global__ __launch_bounds__(256) void proj_mfma_kernel(
    const ushort_t* __restrict__ xTh, const ushort_t* __restrict__ xTl,
    const ushort_t* __restrict__ Whs, const ushort_t* __restrict__ Wls,
    const float* __restrict__ bt, const float* __restrict__ bp,
    const float* __restrict__ bg,
    ushort_t* __restrict__ Qhi, ushort_t* __restrict__ Qlo,
    ushort_t* __restrict__ KhiS, ushort_t* __restrict__ KloS,
    ushort_t* __restrict__ VtS)
{
    __shared__ __align__(16) char smem[65536];
    ushort_t* Wh_l = (ushort_t*)smem;              // [128 o][64 k]
    ushort_t* Wl_l = (ushort_t*)(smem + 16384);
    ushort_t* Xh_l = (ushort_t*)(smem + 32768);    // [128 n][64 k]
    ushort_t* Xl_l = (ushort_t*)(smem + 49152);
    float*    T    = (float*)smem;                 // epilogue [64][132]

    const int tid  = threadIdx.x;
    const int w    = tid >> 6;
    const int lane = tid & 63;
    const int l31  = lane & 31;
    const int h    = lane >> 5;
    const int n0   = blockIdx.x * 128;
    const int og   = blockIdx.y;    // 0 theta, 1 phi, 2 g
    const int b    = blockIdx.z;

    const float* bsel = (og == 0) ? bt : (og == 1) ? bp : bg;

    f32x16 acc[4];
#pragma unroll
    for (int ng = 0; ng < 4; ++ng)
#pragma unroll
        for (int r = 0; r < 16; ++r) acc[ng][r] = 0.f;

    const int ol   = w * 32 + l31;
    const int swzq = l31 & 7;

    for (int kb = 0; kb < 4; ++kb) {
        if (kb > 0) __syncthreads();
#pragma unroll
        for (int p = 0; p < 4; ++p) {
            int e  = p * 2048 + tid * 8;
            int rr = e >> 6;
            int kk = e & 63;
            gload16(Whs + (size_t)(og * 128 + rr) * CINC + kb * 64 + kk, Wh_l + e);
            gload16(Wls + (size_t)(og * 128 + rr) * CINC + kb * 64 + kk, Wl_l + e);
            gload16(xTh + (size_t)(b * NS + n0 + rr) * CINC + kb * 64 + kk, Xh_l + e);
            gload16(xTl + (size_t)(b * NS + n0 + rr) * CINC + kb * 64 + kk, Xl_l + e);
        }
        __syncthreads();

        __builtin_amdgcn_s_setprio(1);
#pragma unroll
        for (int k16 = 0; k16 < 4; ++k16) {
            int c8  = k16 * 2 + h;
            int swz = c8 ^ swzq;
            bf16x8 ah = *reinterpret_cast<const bf16x8*>(&Wh_l[ol * 64 + swz * 8]);
            bf16x8 al = *reinterpret_cast<const bf16x8*>(&Wl_l[ol * 64 + swz * 8]);
#pragma unroll
            for (int ng = 0; ng < 4; ++ng) {
                int nl = ng * 32 + l31;
                bf16x8 xh = *reinterpret_cast<const bf16x8*>(&Xh_l[nl * 64 + swz * 8]);
                bf16x8 xl = *reinterpret_cast<const bf16x8*>(&Xl_l[nl * 64 + swz * 8]);
                acc[ng] = __builtin_amdgcn_mfma_f32_32x32x16_bf16(ah, xh, acc[ng], 0, 0, 0);
                acc[ng] = __builtin_amdgcn_mfma_f32_32x32x16_bf16(ah, xl, acc[ng], 0, 0, 0);
                acc[ng] = __builtin_amdgcn_mfma_f32_32x32x16_bf16(al, xh, acc[ng], 0, 0, 0);
            }
        }
        __builtin_amdgcn_s_setprio(0);
    }

    float bv[16];
#pragma unroll
    for (int r = 0; r < 16; ++r)
        bv[r] = bsel[w * 32 + (r & 3) + 8 * (r >> 2) + 4 * h];

    __syncthreads();

    if (og < 2) {
        ushort_t* H = (og == 0) ? Qhi : KhiS;
        ushort_t* L = (og == 0) ? Qlo : KloS;
#pragma unroll
        for (int pass = 0; pass < 2; ++pass) {
#pragma unroll
            for (int ngh = 0; ngh < 2; ++ngh) {
                int ng = pass * 2 + ngh;
                int nl = ngh * 32 + l31;
#pragma unroll
                for (int r = 0; r < 16; ++r) {
                    int o_in = w * 32 + (r & 3) + 8 * (r >> 2) + 4 * h;
                    T[nl * 132 + o_in] = acc[ng][r] + bv[r];
                }
            }
            __syncthreads();
#pragma unroll
            for (int u = 0; u < 4; ++u) {
                int fi = u * 256 + tid;
                int n  = fi >> 4;
                int j  = fi & 15;
                float4 a0 = ld4(&T[n * 132 + j * 8]);
                float4 a1 = ld4(&T[n * 132 + j * 8 + 4]);
                float v[8] = {a0.x, a0.y, a0.z, a0.w, a1.x, a1.y, a1.z, a1.w};
                uint_t hw[4], lw[4];
                split8(v, hw, lw);
                int n_glob = n0 + pass * 64 + n;
                int idx = (og == 1) ? ((j & 8) | ((j & 7) ^ (n & 7))) : j;
                size_t base = (size_t)(b * NS + n_glob) * CCH + idx * 8;
                *reinterpret_cast<uint4*>(&H[base]) = make_uint4(hw[0], hw[1], hw[2], hw[3]);
                *reinterpret_cast<uint4*>(&L[base]) = make_uint4(lw[0], lw[1], lw[2], lw[3]);
            }
            __syncthreads();
        }
    } else {
#pragma unroll
        for (int pass = 0; pass < 2; ++pass) {
            if ((w >> 1) == pass) {
#pragma unroll
                for (int ng = 0; ng < 4; ++ng) {
                    int nl = ng * 32 + l31;
#pragma unroll
                    for (int r = 0; r < 16; ++r) {
                        int c_loc = (w & 1) * 32 + (r & 3) + 8 * (r >> 2) + 4 * h;
                        T[c_loc * 132 + nl] = acc[ng][r] + bv[r];
                    }
                }
            }
            __syncthreads();
#pragma unroll
            for (int u = 0; u < 4; ++u) {
                int fi = u * 256 + tid;
                int c_loc = fi >> 4;
                int nj    = fi & 15;
                float4 a0 = ld4(&T[c_loc * 132 + nj * 8]);
                float4 a1 = ld4(&T[c_loc * 132 + nj * 8 + 4]);
                int c = pass * 64 + c_loc;
                uint4 wv;
                wv.x = pk2(a0.x, a0.y);
                wv.y = pk2(a0.z, a0.w);
                wv.z = pk2(a1.x, a1.y);
                wv.w = pk2(a1.z, a1.w);
                size_t base = (size_t)(b * CCH + c) * NS + n0 + (nj >> 3) * 64
                            + (((nj & 7) ^ (c & 7)) * 8);
                *reinterpret_cast<uint4*>(&VtS[base]) = wv;
            }
            __syncthreads();
        }
    }
}

// ---------------------------------------------------------------------------
// Kernel 2: MFMA 32x32 flash attention (r7 schedule — best measured).
// QTILE=256 (8 waves x 32 q), KVBLK=64, all staging via global_load_lds,
// fully double-buffered, ONE barrier per iter. LDS 96KB -> 1 block/CU.
// XCD-aware block swizzle. Defer-max. P entirely in registers.
// ---------------------------------------------------------------------------
__global__ __launch_bounds__(512, 2) void attn_kernel(
    const ushort_t* __restrict__ Qhi, const ushort_t* __restrict__ Qlo,
    const ushort_t* __restrict__ KhiS, const ushort_t* __restrict__ KloS,
    const ushort_t* __restrict__ VtS, float* __restrict__ Yp,
    float* __restrict__ ML, int NT)
{
    __shared__ __align__(16) char smem[98304];
    // Kh[2]: 0..32K, Kl[2]: 32K..64K, V[2]: 64K..96K

    const int tid  = threadIdx.x;
    const int w    = tid >> 6;      // wave 0..7 -> q-strip w*32
    const int lane = tid & 63;
    const int l31  = lane & 31;
    const int h    = lane >> 5;

    // XCD-aware swizzle (bijective for the 256-block nsplit=4 grid):
    // each XCD owns 2 complete (b,sp) KV streams.
    int qx, sp, b;
    {
        int lin = (blockIdx.z * gridDim.y + blockIdx.y) * gridDim.x + blockIdx.x;
        if (gridDim.x * gridDim.y * gridDim.z == 256) {
            int xcd  = lin & 7;
            int idx  = lin >> 3;           // 0..31
            int pair = xcd * 2 + (idx >> 4);
            qx = idx & 15;
            b  = pair >> 2;
            sp = pair & 3;
        } else {
            qx = blockIdx.x; sp = blockIdx.y; b = blockIdx.z;
        }
    }
    const int n0 = qx * 256;

    // Q fragments in registers: B-frag col q = l31, k-elems c = cst*16 + h*8 + i
    bf16x8 qh[8], ql[8];
    {
        const ushort_t* qrh = Qhi + (size_t)(b * NS + n0 + w * 32 + l31) * CCH;
        const ushort_t* qrl = Qlo + (size_t)(b * NS + n0 + w * 32 + l31) * CCH;
#pragma unroll
        for (int cst = 0; cst < 8; ++cst) {
            qh[cst] = *reinterpret_cast<const bf16x8*>(qrh + cst * 16 + h * 8);
            ql[cst] = *reinterpret_cast<const bf16x8*>(qrl + cst * 16 + h * 8);
        }
    }

    f32x16 yacc[4];
#pragma unroll
    for (int cb = 0; cb < 4; ++cb)
#pragma unroll
        for (int r = 0; r < 16; ++r) yacc[cb][r] = 0.f;
    float m_run = -1e30f, l_run = 0.f;

    const ushort_t* Khg = KhiS + (size_t)b * NS * CCH;
    const ushort_t* Klg = KloS + (size_t)b * NS * CCH;
    const ushort_t* Vtg = VtS + (size_t)b * CCH * NS;

    const int ktbase = sp * NT;

    auto gload_tile = [&](int ktg, int bi) {
        ushort_t* kh = (ushort_t*)(smem + bi * 16384);
        ushort_t* kl = (ushort_t*)(smem + 32768 + bi * 16384);
        ushort_t* vb = (ushort_t*)(smem + 65536 + bi * 16384);
        const size_t koff = (size_t)ktg * 8192;   // 64 rows * 128 c (ushorts)
        const int m0 = ktg * 64;
#pragma unroll
        for (int i = 0; i < 2; ++i) {
            int off = i * 4096 + tid * 8;
            gload16(Khg + koff + off, kh + off);
            gload16(Klg + koff + off, kl + off);
            int cr = off >> 6;
            int cw = off & 63;
            gload16(Vtg + (size_t)cr * NS + m0 + cw, vb + off);
        }
    };

    // prologue
    gload_tile(ktbase, 0);
    __syncthreads();   // implicit vmcnt drain

    const int swzq = l31 & 7;

    for (int kt = 0; kt < NT; ++kt) {
        const int cur = kt & 1;
        const bool more = (kt + 1 < NT);
        if (more) gload_tile(ktbase + kt + 1, cur ^ 1);

        const ushort_t* Kh = (const ushort_t*)(smem + cur * 16384);
        const ushort_t* Kl = (const ushort_t*)(smem + 32768 + cur * 16384);
        const ushort_t* Vl = (const ushort_t*)(smem + 65536 + cur * 16384);

        // ---- QK^T: S^T[64k][32q], 3-pass split-bf16, 32x32x16 MFMA
        f32x16 sacc[2];
#pragma unroll
        for (int k2 = 0; k2 < 2; ++k2)
#pragma unroll
            for (int r = 0; r < 16; ++r) sacc[k2][r] = 0.f;

        __builtin_amdgcn_s_setprio(1);
#pragma unroll
        for (int cst = 0; cst < 8; ++cst) {
            int cc  = cst * 2 + h;
            int swz = (cc & 8) | ((cc & 7) ^ swzq);
#pragma unroll
            for (int k2 = 0; k2 < 2; ++k2) {
                int addr = (k2 * 32 + l31) * 128 + swz * 8;
                bf16x8 ah = *reinterpret_cast<const bf16x8*>(&Kh[addr]);
                bf16x8 al = *reinterpret_cast<const bf16x8*>(&Kl[addr]);
                sacc[k2] = __builtin_amdgcn_mfma_f32_32x32x16_bf16(ah, qh[cst], sacc[k2], 0, 0, 0);
                sacc[k2] = __builtin_amdgcn_mfma_f32_32x32x16_bf16(al, qh[cst], sacc[k2], 0, 0, 0);
                sacc[k2] = __builtin_amdgcn_mfma_f32_32x32x16_bf16(ah, ql[cst], sacc[k2], 0, 0, 0);
            }
        }
        __builtin_amdgcn_s_setprio(0);

        // ---- online softmax (lane owns q = w*32+l31; 32 of 64 k in-lane)
        float mx = sacc[0][0];
#pragma unroll
        for (int r = 1; r < 16; ++r) mx = fmaxf(mx, sacc[0][r]);
#pragma unroll
        for (int r = 0; r < 16; ++r) mx = fmaxf(mx, sacc[1][r]);
        mx = fmaxf(mx, __shfl_xor(mx, 32));

        const bool defer = __all(mx - m_run <= 8.0f);
        float mref, alpha;
        if (defer) { mref = m_run; alpha = 1.0f; }
        else       { mref = fmaxf(m_run, mx); alpha = __expf(m_run - mref); }

        // ---- P = exp(S - mref), pack to PV B-frags entirely in registers
        bf16x8 pb[4];
        float psum = 0.f;
#pragma unroll
        for (int k2 = 0; k2 < 2; ++k2) {
            float pe[16];
#pragma unroll
            for (int r = 0; r < 16; ++r) {
                pe[r] = __expf(sacc[k2][r] - mref);
                psum += pe[r];
            }
#pragma unroll
            for (int a = 0; a < 2; ++a) {
                uint_t w0 = pk2(pe[8 * a + 0], pe[8 * a + 1]);
                uint_t w1 = pk2(pe[8 * a + 2], pe[8 * a + 3]);
                uint_t w2 = pk2(pe[8 * a + 4], pe[8 * a + 5]);
                uint_t w3 = pk2(pe[8 * a + 6], pe[8 * a + 7]);
                uint_t s0 = (uint_t)__shfl_xor((int)w0, 32);
                uint_t s1 = (uint_t)__shfl_xor((int)w1, 32);
                uint_t s2 = (uint_t)__shfl_xor((int)w2, 32);
                uint_t s3 = (uint_t)__shfl_xor((int)w3, 32);
                uint_t u0 = h ? s2 : w0;
                uint_t u1 = h ? s3 : w1;
                uint_t u2 = h ? w2 : s0;
                uint_t u3 = h ? w3 : s1;
                uint4 packed = make_uint4(u0, u1, u2, u3);
                pb[k2 * 2 + a] = *reinterpret_cast<bf16x8*>(&packed);
            }
        }
        psum += __shfl_xor(psum, 32);

        if (defer) {
            l_run += psum;
        } else {
            l_run = l_run * alpha + psum;
            m_run = mref;
#pragma unroll
            for (int cb = 0; cb < 4; ++cb)
#pragma unroll
                for (int r = 0; r < 16; ++r) yacc[cb][r] *= alpha;
        }

        // ---- PV: Y^T[c][q] += V^T x P^T (A = V-frags, B = pb)
        __builtin_amdgcn_s_setprio(1);
#pragma unroll
        for (int cb = 0; cb < 4; ++cb) {
            int crow = (cb * 32 + l31) * 64;
#pragma unroll
            for (int ks = 0; ks < 4; ++ks) {
                int kc = ks * 2 + h;
                bf16x8 av = *reinterpret_cast<const bf16x8*>(&Vl[crow + (kc ^ swzq) * 8]);
                yacc[cb] = __builtin_amdgcn_mfma_f32_32x32x16_bf16(av, pb[ks], yacc[cb], 0, 0, 0);
            }
        }
        __builtin_amdgcn_s_setprio(0);

        __syncthreads();   // readers done with cur; prefetch (cur^1) drained
    }

    // ---- epilogue: coalesced unnormalized-Y store via staged LDS (4 passes)
    float* stage = (float*)smem;   // [64][132]
    float* Ybase = Yp + ((size_t)(sp * BB + b) * NS + n0) * CCH;
#pragma unroll
    for (int pass = 0; pass < 4; ++pass) {
        if ((w >> 1) == pass) {
            int qrow = (w & 1) * 32 + l31;
#pragma unroll
            for (int cb = 0; cb < 4; ++cb)
#pragma unroll
                for (int r = 0; r < 16; ++r) {
                    int c = cb * 32 + (r & 3) + 8 * (r >> 2) + 4 * h;
                    stage[qrow * 132 + c] = yacc[cb][r];
                }
        }
        __syncthreads();
#pragma unroll
        for (int u = 0; u < 4; ++u) {
            int idx = u * 512 + tid;
            int row = idx >> 5;
            int c4  = idx & 31;
            st4(&Ybase[(size_t)(pass * 64 + row) * CCH + c4 * 4],
                ld4(&stage[row * 132 + c4 * 4]));
        }
        __syncthreads();
    }
    if (h == 0) {
        size_t mi = ((size_t)(sp * BB + b) * NS + n0 + w * 32 + l31) * 2;
        ML[mi + 0] = m_run;
        ML[mi + 1] = l_run;
    }
}

// ---------------------------------------------------------------------------
// Kernel 2b: merge KV-split partials -> normalized Ym, split bf16, swizzled.
// ---------------------------------------------------------------------------
__global__ __launch_bounds__(256) void merge_kernel(
    const float* __restrict__ Yp, const float* __restrict__ ML,
    ushort_t* __restrict__ Ymh, ushort_t* __restrict__ Yml, int nsplit)
{
    const int total = BB * NS * (CCH / 8);    // 262144
    for (int t = blockIdx.x * 256 + threadIdx.x; t < total;
         t += gridDim.x * 256) {
        int b = t >> 16;
        int r = t & 65535;
        int n = r >> 4;
        int j = r & 15;

        float ms[4], ls[4];
        float m = -1e30f;
#pragma unroll
        for (int s = 0; s < 4; ++s) {
            if (s < nsplit) {
                size_t mi = ((size_t)(s * BB + b) * NS + n) * 2;
                ms[s] = ML[mi + 0];
                ls[s] = ML[mi + 1];
                m = fmaxf(m, ms[s]);
            }
        }
        float den = 0.f;
        float wt[4];
#pragma unroll
        for (int s = 0; s < 4; ++s) {
            if (s < nsplit) {
                wt[s] = __expf(ms[s] - m);
                den += ls[s] * wt[s];
            }
        }
        float inv = 1.0f / den;

        float acc[8] = {0.f, 0.f, 0.f, 0.f, 0.f, 0.f, 0.f, 0.f};
#pragma unroll
        for (int s = 0; s < 4; ++s) {
            if (s < nsplit) {
                float a = wt[s] * inv;
                const float* yr = &Yp[((size_t)(s * BB + b) * NS + n) * CCH + j * 8];
                float4 y0 = ld4(yr);
                float4 y1 = ld4(yr + 4);
                acc[0] += a * y0.x; acc[1] += a * y0.y;
                acc[2] += a * y0.z; acc[3] += a * y0.w;
                acc[4] += a * y1.x; acc[5] += a * y1.y;
                acc[6] += a * y1.z; acc[7] += a * y1.w;
            }
        }
        uint_t hw[4], lw[4];
        split8(acc, hw, lw);
        size_t base = (size_t)(b * NS + n) * CCH + (j >> 3) * 64
                    + (((j & 7) ^ (n & 7)) * 8);
        *reinterpret_cast<uint4*>(&Ymh[base]) = make_uint4(hw[0], hw[1], hw[2], hw[3]);
        *reinterpret_cast<uint4*>(&Yml[base]) = make_uint4(lw[0], lw[1], lw[2], lw[3]);
    }
}

// ---------------------------------------------------------------------------
// Kernel 3: z = Wz . Ym + bz via 3-pass split-bf16 MFMA, + LN partials.
// ---------------------------------------------------------------------------
__global__ __launch_bounds__(256) void zgemm_kernel(
    const ushort_t* __restrict__ Ymh, const ushort_t* __restrict__ Yml,
    const ushort_t* __restrict__ Wzh, const ushort_t* __restrict__ Wzl,
    const float* __restrict__ bz, float* __restrict__ Z,
    float* __restrict__ partials)
{
    __shared__ __align__(16) char smem[65536];
    ushort_t* Wh_l = (ushort_t*)smem;
    ushort_t* Wl_l = (ushort_t*)(smem + 16384);
    ushort_t* Yh_l = (ushort_t*)(smem + 32768);
    ushort_t* Yl_l = (ushort_t*)(smem + 49152);
    __shared__ float red[8];

    const int tid  = threadIdx.x;
    const int w    = tid >> 6;
    const int lane = tid & 63;
    const int l31  = lane & 31;
    const int h    = lane >> 5;
    const int n0   = blockIdx.x * 128;
    const int o0   = blockIdx.y * 128;
    const int b    = blockIdx.z;

    f32x16 acc[4];
#pragma unroll
    for (int ng = 0; ng < 4; ++ng)
#pragma unroll
        for (int r = 0; r < 16; ++r) acc[ng][r] = 0.f;

    const int ol   = w * 32 + l31;
    const int swzq = l31 & 7;

    for (int kb = 0; kb < 2; ++kb) {
        if (kb > 0) __syncthreads();
#pragma unroll
        for (int p = 0; p < 4; ++p) {
            int e  = p * 2048 + tid * 8;
            int rr = e >> 6;
            int kk = e & 63;
            gload16(Wzh + (size_t)(o0 + rr) * CCH + kb * 64 + kk, Wh_l + e);
            gload16(Wzl + (size_t)(o0 + rr) * CCH + kb * 64 + kk, Wl_l + e);
            gload16(Ymh + (size_t)(b * NS + n0 + rr) * CCH + kb * 64 + kk, Yh_l + e);
            gload16(Yml + (size_t)(b * NS + n0 + rr) * CCH + kb * 64 + kk, Yl_l + e);
        }
        __syncthreads();

        __builtin_amdgcn_s_setprio(1);
#pragma unroll
        for (int k16 = 0; k16 < 4; ++k16) {
            int c8  = k16 * 2 + h;
            int swz = c8 ^ swzq;
            bf16x8 ah = *reinterpret_cast<const bf16x8*>(&Wh_l[ol * 64 + swz * 8]);
            bf16x8 al = *reinterpret_cast<const bf16x8*>(&Wl_l[ol * 64 + swz * 8]);
#pragma unroll
            for (int ng = 0; ng < 4; ++ng) {
                int nl = ng * 32 + l31;
                bf16x8 yh = *reinterpret_cast<const bf16x8*>(&Yh_l[nl * 64 + swz * 8]);
                bf16x8 yl = *reinterpret_cast<const bf16x8*>(&Yl_l[nl * 64 + swz * 8]);
                acc[ng] = __builtin_amdgcn_mfma_f32_32x32x16_bf16(ah, yh, acc[ng], 0, 0, 0);
                acc[ng] = __builtin_amdgcn_mfma_f32_32x32x16_bf16(ah, yl, acc[ng], 0, 0, 0);
                acc[ng] = __builtin_amdgcn_mfma_f32_32x32x16_bf16(al, yh, acc[ng], 0, 0, 0);
            }
        }
        __builtin_amdgcn_s_setprio(0);
    }

    float s = 0.f, s2 = 0.f;
#pragma unroll
    for (int r = 0; r < 16; ++r) {
        int o = o0 + w * 32 + (r & 3) + 8 * (r >> 2) + 4 * h;
        float bias = bz[o];
        float* zrow = &Z[(size_t)(b * CINC + o) * NS + n0 + l31];
#pragma unroll
        for (int ng = 0; ng < 4; ++ng) {
            float v = acc[ng][r] + bias;
            zrow[ng * 32] = v;
            s  += v;
            s2 += v * v;
        }
    }
#pragma unroll
    for (int off = 1; off < 64; off <<= 1) {
        s  += __shfl_xor(s, off);
        s2 += __shfl_xor(s2, off);
    }
    if (lane == 0) { red[w * 2] = s; red[w * 2 + 1] = s2; }
    __syncthreads();
    if (tid == 0) {
        float ts  = red[0] + red[2] + red[4] + red[6];
        float ts2 = red[1] + red[3] + red[5] + red[7];
        int pidx = (b * 2 + blockIdx.y) * 32 + blockIdx.x;
        partials[pidx * 2 + 0] = ts;
        partials[pidx * 2 + 1] = ts2;
    }
}

// ---------------------------------------------------------------------------
// Kernel 4: reduce partials (64 per batch) -> per-batch (mean, rstd).
// ---------------------------------------------------------------------------
__global__ void ln_stats_kernel(const float* __restrict__ partials,
                                float* __restrict__ stats)
{
    const int b = blockIdx.x;
    const int t = threadIdx.x;  // 64
    float s  = partials[(size_t)(b * 64 + t) * 2 + 0];
    float s2 = partials[(size_t)(b * 64 + t) * 2 + 1];
#pragma unroll
    for (int off = 1; off < 64; off <<= 1) {
        s  += __shfl_xor(s, off);
        s2 += __shfl_xor(s2, off);
    }
    if (t == 0) {
        const float M = 1048576.f;
        float mean = s / M;
        float var  = s2 / M - mean * mean;
        stats[b * 2 + 0] = mean;
        stats[b * 2 + 1] = rsqrtf(var + LN_EPS);
    }
}

// ---------------------------------------------------------------------------
// Kernel 5: out = (z - mean)*rstd*gamma + beta + x
// ---------------------------------------------------------------------------
__global__ __launch_bounds__(256) void final_kernel(
    const float* __restrict__ Z, const float* __restrict__ x,
    const float* __restrict__ gamma, const float* __restrict__ beta,
    const float* __restrict__ stats, float* __restrict__ out)
{
    const int total4 = BB * CINC * NS / 4;
    for (int i4 = blockIdx.x * 256 + threadIdx.x; i4 < total4;
         i4 += gridDim.x * 256) {
        int b  = i4 >> 18;
        int r4 = i4 & ((1 << 18) - 1);
        float mean = stats[b * 2 + 0];
        float rstd = stats[b * 2 + 1];
        float4 zv = ld4(&Z[(size_t)i4 * 4]);
        float4 xv = ld4(&x[(size_t)i4 * 4]);
        float4 gv = ld4(&gamma[(size_t)r4 * 4]);
        float4 bv = ld4(&beta[(size_t)r4 * 4]);
        float4 o;
        o.x = (zv.x - mean) * rstd * gv.x + bv.x + xv.x;
        o.y = (zv.y - mean) * rstd * gv.y + bv.y + xv.y;
        o.z = (zv.z - mean) * rstd * gv.z + bv.z + xv.z;
        o.w = (zv.w - mean) * rstd * gv.w + bv.w + xv.w;
        st4(&out[(size_t)i4 * 4], o);
    }
}

extern "C" void kernel_launch(void* const* d_in, const int* in_sizes, int n_in,
                              void* d_out, int out_size, void* d_ws, size_t ws_size,
                              hipStream_t stream)
{
    const float* x     = (const float*)d_in[0];
    const float* Wg    = (const float*)d_in[1];
    const float* bg    = (const float*)d_in[2];
    const float* Wt    = (const float*)d_in[3];
    const float* bt    = (const float*)d_in[4];
    const float* Wp    = (const float*)d_in[5];
    const float* bp    = (const float*)d_in[6];
    const float* Wz    = (const float*)d_in[7];
    const float* bz    = (const float*)d_in[8];
    const float* gamma = (const float*)d_in[9];
    const float* beta  = (const float*)d_in[10];
    float* out = (float*)d_out;

    const size_t SZH = (size_t)BB * NS * CCH * sizeof(ushort_t);  // 4 MB
    const size_t WZB = (size_t)CINC * CCH * sizeof(ushort_t);     // 64 KB
    const size_t need4 = 5 * SZH
                       + (size_t)4 * BB * NS * CCH * sizeof(float)
                       + (size_t)4 * BB * NS * 2 * sizeof(float)
                       + (size_t)BB * 64 * 2 * sizeof(float)
                       + 2 * WZB + 512;
    const int nsplit = (ws_size >= need4) ? 4 : 2;
    const int NT = (NS / 64) / nsplit;   // 64-key tiles per split

    char* p = (char*)d_ws;
    ushort_t* Qhi  = (ushort_t*)p; p += SZH;
    ushort_t* Qlo  = (ushort_t*)p; p += SZH;
    ushort_t* KhiS = (ushort_t*)p; p += SZH;
    ushort_t* KloS = (ushort_t*)p; p += SZH;
    ushort_t* VtS  = (ushort_t*)p; p += SZH;
    float* Yp = (float*)p; p += (size_t)nsplit * BB * NS * CCH * sizeof(float);
    float* ML = (float*)p; p += (size_t)nsplit * BB * NS * 2 * sizeof(float);
    float* partials = (float*)p; p += BB * 64 * 2 * sizeof(float);
    float* stats    = (float*)p; p += 64;
    ushort_t* Wzh = (ushort_t*)p; p += WZB;
    ushort_t* Wzl = (ushort_t*)p;

    // aliases (stream-ordered lifetimes):
    ushort_t* Ymh = (ushort_t*)Qhi;    // Q dead after attn
    ushort_t* Yml = (ushort_t*)Qlo;
    float*    Z   = (float*)Yp;        // Yp dead after merge

    // proj scratch aliases into Yp (dead until attn writes it)
    ushort_t* xTh = (ushort_t*)Yp;
    ushort_t* xTl = xTh + (size_t)BB * NS * CINC;
    ushort_t* Whs = (ushort_t*)((char*)Yp + 2 * (size_t)BB * NS * CINC * 2);
    ushort_t* Wls = Whs + (size_t)384 * CINC;

    split_kernel<<<dim3(NS / 64, CINC / 64, BB), 256, 0, stream>>>(x, xTh, xTl);
    wsplit_all_kernel<<<dim3(64), 256, 0, stream>>>(Wt, Wp, Wg, Wz,
                                                    Whs, Wls, Wzh, Wzl);
    proj_mfma_kernel<<<dim3(NS / 128, 3, BB), 256, 0, stream>>>(
        xTh, xTl, Whs, Wls, bt, bp, bg, Qhi, Qlo, KhiS, KloS, VtS);
    attn_kernel<<<dim3(NS / 256, nsplit, BB), 512, 0, stream>>>(
        Qhi, Qlo, KhiS, KloS, VtS, Yp, ML, NT);
    merge_kernel<<<dim3(1024), 256, 0, stream>>>(Yp, ML, Ymh, Yml, nsplit);
    zgemm_kernel<<<dim3(NS / 128, 2, BB), 256, 0, stream>>>(
        Ymh, Yml, Wzh, Wzl, bz, Z, partials);
    ln_stats_kernel<<<dim3(BB), 64, 0, stream>>>(partials, stats);
    final_kernel<<<dim3(2048), 256, 0, stream>>>(Z, x, gamma, beta, stats, out);
}